// Round 13
// baseline (169.349 us; speedup 1.0000x reference)
//
#include <hip/hip_runtime.h>
#include <hip/hip_bf16.h>
#include <math.h>

#define NN 512
#define DIMX 384
#define HH 8
#define PAIRD 128

#define SCALAR_SCALE 0.144337567297406f   // (3*16)^-0.5
#define POINT_SCALE  0.136082763487954f   // (12*4.5)^-0.5
#define PAIR_SCALE   0.577350269189626f   // 3^-0.5

#define KSL 8
#define KPER 160      // 1280 / KSL
#define PCH 1264      // floats per (i, jc) attn partial chunk

// ---------------- Kernel 1a: unified projection GEMM ----------------
__global__ __launch_bounds__(256) void k_proj_gemm(
    const float* __restrict__ x,
    const float* __restrict__ Wsq, const float* __restrict__ Wsk, const float* __restrict__ Wsv,
    const float* __restrict__ Wpq, const float* __restrict__ Wpk, const float* __restrict__ Wpv,
    float* __restrict__ qs, float* __restrict__ ks, float* __restrict__ vs,
    float* __restrict__ plq, float* __restrict__ plk, float* __restrict__ plv)
{
    const int m0 = blockIdx.x * 64;
    const int t  = blockIdx.y;   // 0..20
    int ldw, c0;
    const float* W;
    float* out;
    if (t < 12) {
        const float* Ws[3] = {Wsq, Wsk, Wsv};
        float* outs[3] = {qs, ks, vs};
        W = Ws[t >> 2]; out = outs[t >> 2]; c0 = (t & 3) * 32; ldw = 128;
    } else {
        const int u = t - 12;
        const float* Wp[3] = {Wpq, Wpk, Wpv};
        float* outp[3] = {plq, plk, plv};
        W = Wp[u / 3]; out = outp[u / 3]; c0 = (u % 3) * 32; ldw = 96;
    }
    const int tid = threadIdx.x;
    __shared__ float xs[32][68];
    __shared__ float Bs[32][36];
    const int tx = tid & 15, ty = tid >> 4;
    float acc[4][2] = {};

    for (int kt = 0; kt < DIMX; kt += 32) {
        #pragma unroll
        for (int it = 0; it < 2; ++it) {
            int l = tid + it * 256;
            int row = l >> 3, kq = l & 7;
            float4 a = *(const float4*)&x[(size_t)(m0 + row) * DIMX + kt + kq * 4];
            xs[kq*4+0][row] = a.x; xs[kq*4+1][row] = a.y;
            xs[kq*4+2][row] = a.z; xs[kq*4+3][row] = a.w;
        }
        {
            int kk = tid >> 3, nq = tid & 7;
            float4 b = *(const float4*)&W[(size_t)(kt + kk) * ldw + c0 + nq * 4];
            *(float4*)&Bs[kk][nq * 4] = b;
        }
        __syncthreads();
        #pragma unroll
        for (int k = 0; k < 32; ++k) {
            float4 a  = *(const float4*)&xs[k][ty * 4];
            float2 bv = *(const float2*)&Bs[k][tx * 2];
            acc[0][0] += a.x * bv.x; acc[0][1] += a.x * bv.y;
            acc[1][0] += a.y * bv.x; acc[1][1] += a.y * bv.y;
            acc[2][0] += a.z * bv.x; acc[2][1] += a.z * bv.y;
            acc[3][0] += a.w * bv.x; acc[3][1] += a.w * bv.y;
        }
        __syncthreads();
    }
    #pragma unroll
    for (int r = 0; r < 4; ++r) {
        float2 v = make_float2(acc[r][0], acc[r][1]);
        *(float2*)&out[(size_t)(m0 + ty * 4 + r) * ldw + c0 + tx * 2] = v;
    }
}

// ---------------- Kernel 1b: frame transform ----------------
__global__ __launch_bounds__(256) void k_frames(
    const float* __restrict__ plq, const float* __restrict__ plk, const float* __restrict__ plv,
    const float* __restrict__ rot, const float* __restrict__ trans,
    float* __restrict__ qp, float* __restrict__ kp, float* __restrict__ vp)
{
    int g = blockIdx.x * 256 + threadIdx.x;
    int m = g >> 14;
    int rem = g & 16383;
    int i = rem >> 5;
    int p = rem & 31;
    const float* pl = (m == 0 ? plq : (m == 1 ? plk : plv));
    float*       o  = (m == 0 ? qp  : (m == 1 ? kp  : vp));
    const float* l = &pl[(size_t)i * 96 + p * 3];
    const float* R = &rot[(size_t)i * 9];
    const float* T = &trans[(size_t)i * 3];
    float l0 = l[0], l1 = l[1], l2 = l[2];
    float* op = o + (size_t)i * 96 + p * 3;
    #pragma unroll
    for (int c = 0; c < 3; ++c)
        op[c] = l0 * R[0 * 3 + c] + l1 * R[1 * 3 + c] + l2 * R[2 * 3 + c] + T[c];
}

// ---------------- Kernel 2: fused attention ----------------
// block = (jc, i). Phase 0: chunk bias GEMV (register butterfly) -> LDS (pair's
// one cold HBM read). Phase 1: 128 logits -> LDS. Phase 2: one softmax.
// Phase 3: r8-style j-split accumulation, FULL unroll (deep load pipeline; VGPR
// high is intentional - r8 proved 84.6us at VGPR 164, no spill, no cap).
__global__ __launch_bounds__(256) void k_attn(
    const float* __restrict__ pair,
    const float* __restrict__ qs, const float* __restrict__ ks,
    const float* __restrict__ qp, const float* __restrict__ kp,
    const float* __restrict__ vs, const float* __restrict__ vp,
    const float* __restrict__ Wpair, const float* __restrict__ bpair,
    const float* __restrict__ pwts,
    float* __restrict__ attnp)
{
    const int jc  = blockIdx.x;      // 0..3
    const int i   = blockIdx.y;      // 0..511
    const int tid = threadIdx.x;

    __shared__ float smem[4992];     // ~20 KB; lg/bias_s aliased by reduce tail
    float* lg     = smem;            // [8][132] raw logits -> weights
    float* qs_s   = smem + 1056;     // [128]
    float* qp_s   = smem + 1184;     // [96]
    float* bias_s = smem + 1280;     // [8][132] chunk pair-bias

    if (tid < 32) ((float4*)qs_s)[tid] = ((const float4*)(qs + (size_t)i * 128))[tid];
    if (tid < 24) ((float4*)qp_s)[tid] = ((const float4*)(qp + (size_t)i * 96))[tid];

    // ---- Phase 0: bias GEMV for this chunk's 128 rows (pair cold read) ----
    {
        const int b  = tid >> 5;     // row group 0..7
        const int pq = tid & 31;     // p-slice (float4 index)
        float wv[32];
        {
            const float4* W4 = (const float4*)(Wpair + pq * 32);
            #pragma unroll
            for (int q = 0; q < 8; ++q) {
                float4 w = W4[q];
                wv[q * 4 + 0] = w.x; wv[q * 4 + 1] = w.y;
                wv[q * 4 + 2] = w.z; wv[q * 4 + 3] = w.w;
            }
        }
        #pragma unroll
        for (int it = 0; it < 4; ++it) {
            const int j0 = it * 32;
            float cur[32];           // [r 4][h 8] partials
            #pragma unroll
            for (int r = 0; r < 4; ++r) {
                const int j = jc * 128 + j0 + b + r * 8;
                float4 a = *(const float4*)&pair[((size_t)i * NN + j) * PAIRD + pq * 4];
                float ac[4] = {a.x, a.y, a.z, a.w};
                #pragma unroll
                for (int h = 0; h < 8; ++h) {
                    float s = 0.f;
                    #pragma unroll
                    for (int p = 0; p < 4; ++p) s += ac[p] * wv[p * 8 + h];
                    cur[r * 8 + h] = s;
                }
            }
            #pragma unroll
            for (int s5 = 0; s5 < 5; ++s5) {
                const int m = 16 >> s5;
                const bool up = (pq & m) != 0;
                #pragma unroll
                for (int u = 0; u < (16 >> s5); ++u) {
                    float lo = cur[u], hi = cur[u + (16 >> s5)];
                    float send = up ? lo : hi;
                    float got  = __shfl_xor(send, m);
                    cur[u] = up ? (hi + got) : (lo + got);
                }
            }
            bias_s[(pq & 7) * 132 + (j0 + b + (pq >> 3) * 8)] = cur[0];
        }
    }
    __syncthreads();

    const int g   = tid & 7;         // phase 1: head
    const int jjL = tid >> 3;        // phase 1: j-lane (0..31)
    const int h2  = tid >> 5;        // phase 2: head / phase 3: j-group
    const int jj2 = tid & 31;        // phase 2: j-lane / phase 3: float4 channel
    const int jg  = h2, pq = jj2;

    // ---- Phase 1: 4 independent logits per thread ----
    {
        const float bp_h = bpair[g];
        const float pw_h = log1pf(__expf(pwts[g]));
        const float4* qr4 = (const float4*)&qs_s[g * 16];
        const float4* qp4 = (const float4*)&qp_s[g * 12];
        #pragma unroll
        for (int t = 0; t < 4; ++t) {
            const int jl = t * 32 + jjL;
            const int j  = jc * 128 + jl;
            float bv = bias_s[g * 132 + jl];
            float sc = 0.f;
            const float4* kr4 = (const float4*)(ks + (size_t)j * 128 + g * 16);
            #pragma unroll
            for (int q = 0; q < 4; ++q) {
                float4 kq = kr4[q], qq = qr4[q];
                sc += qq.x * kq.x + qq.y * kq.y + qq.z * kq.z + qq.w * kq.w;
            }
            float d2 = 0.f;
            const float4* kp4 = (const float4*)(kp + (size_t)j * 96 + g * 12);
            #pragma unroll
            for (int q = 0; q < 3; ++q) {
                float4 kq = kp4[q], qq = qp4[q];
                float dx = qq.x - kq.x, dy = qq.y - kq.y, dz = qq.z - kq.z, dw = qq.w - kq.w;
                d2 += dx * dx + dy * dy + dz * dz + dw * dw;
            }
            lg[g * 132 + jl] = sc * SCALAR_SCALE + (bv + bp_h) * PAIR_SCALE
                             - 0.5f * POINT_SCALE * pw_h * d2;
        }
    }
    __syncthreads();

    // ---- Phase 2: one softmax per head row (32 lanes each) ----
    float m_run, l_run;
    {
        float v0 = lg[h2 * 132 + jj2],      v1 = lg[h2 * 132 + 32 + jj2];
        float v2 = lg[h2 * 132 + 64 + jj2], v3 = lg[h2 * 132 + 96 + jj2];
        float m = fmaxf(fmaxf(v0, v1), fmaxf(v2, v3));
        #pragma unroll
        for (int off = 16; off > 0; off >>= 1) m = fmaxf(m, __shfl_xor(m, off));
        float e0 = __expf(v0 - m), e1 = __expf(v1 - m);
        float e2 = __expf(v2 - m), e3 = __expf(v3 - m);
        float s = e0 + e1 + e2 + e3;
        #pragma unroll
        for (int off = 16; off > 0; off >>= 1) s += __shfl_xor(s, off);
        m_run = m; l_run = s;
        lg[h2 * 132 + jj2]      = e0; lg[h2 * 132 + 32 + jj2] = e1;
        lg[h2 * 132 + 64 + jj2] = e2; lg[h2 * 132 + 96 + jj2] = e3;
    }
    __syncthreads();

    // ---- Phase 3: j-split accumulation, FULL unroll (deep load pipeline) ----
    float4 accP[8];
    #pragma unroll
    for (int z = 0; z < 8; ++z) accP[z] = make_float4(0, 0, 0, 0);
    float4 accS = make_float4(0, 0, 0, 0);
    float4 accV = make_float4(0, 0, 0, 0);
    {
        const float4* pair4 = (const float4*)pair;
        const float4* vs4   = (const float4*)vs;
        const float4* vp4   = (const float4*)vp;
        #pragma unroll
        for (int jo = 0; jo < 16; ++jo) {
            const int jl = jo * 8 + jg;
            const int jglob = jc * 128 + jl;
            float4 pr = pair4[((size_t)i * NN + jglob) * 32 + pq];
            #pragma unroll
            for (int z = 0; z < 8; ++z) {
                float a = lg[z * 132 + jl];
                accP[z].x += a * pr.x; accP[z].y += a * pr.y;
                accP[z].z += a * pr.z; accP[z].w += a * pr.w;
            }
            {
                float a = lg[(pq >> 2) * 132 + jl];
                float4 v = vs4[(size_t)jglob * 32 + pq];
                accS.x += a * v.x; accS.y += a * v.y; accS.z += a * v.z; accS.w += a * v.w;
            }
            if (pq < 24) {
                float a = lg[(pq / 3) * 132 + jl];
                float4 v = vp4[(size_t)jglob * 24 + pq];
                accV.x += a * v.x; accV.y += a * v.y; accV.z += a * v.z; accV.w += a * v.w;
            }
        }
    }
    __syncthreads();                                  // lg/bias_s dead; safe to alias

    float* attnc = attnp + ((size_t)i * 4 + jc) * PCH;
    if (jj2 == 0) { attnc[1248 + h2] = m_run; attnc[1256 + h2] = l_run; }

    // cross-wave combine: xor-32, then 4 group-pairs via LDS
    #pragma unroll
    for (int z = 0; z < 8; ++z) {
        accP[z].x += __shfl_xor(accP[z].x, 32); accP[z].y += __shfl_xor(accP[z].y, 32);
        accP[z].z += __shfl_xor(accP[z].z, 32); accP[z].w += __shfl_xor(accP[z].w, 32);
    }
    accS.x += __shfl_xor(accS.x, 32); accS.y += __shfl_xor(accS.y, 32);
    accS.z += __shfl_xor(accS.z, 32); accS.w += __shfl_xor(accS.w, 32);
    accV.x += __shfl_xor(accV.x, 32); accV.y += __shfl_xor(accV.y, 32);
    accV.z += __shfl_xor(accV.z, 32); accV.w += __shfl_xor(accV.w, 32);

    float4* redP = (float4*)smem;               // [4][8][32]
    float4* redS = (float4*)(smem + 4096);      // [4][32]
    float4* redV = (float4*)(smem + 4608);      // [4][24]
    const int jgp = jg >> 1;
    if ((jg & 1) == 0) {
        #pragma unroll
        for (int z = 0; z < 8; ++z) redP[(jgp * 8 + z) * 32 + pq] = accP[z];
        redS[jgp * 32 + pq] = accS;
        if (pq < 24) redV[jgp * 24 + pq] = accV;
    }
    __syncthreads();

    {
        const int z = tid >> 5, p4 = tid & 31;
        float4 s = redP[z * 32 + p4];
        #pragma unroll
        for (int gg = 1; gg < 4; ++gg) {
            float4 v = redP[(gg * 8 + z) * 32 + p4];
            s.x += v.x; s.y += v.y; s.z += v.z; s.w += v.w;
        }
        *(float4*)&attnc[z * 128 + p4 * 4] = s;
    }
    if (tid < 32) {
        float4 s = redS[tid];
        #pragma unroll
        for (int gg = 1; gg < 4; ++gg) {
            float4 v = redS[gg * 32 + tid];
            s.x += v.x; s.y += v.y; s.z += v.z; s.w += v.w;
        }
        *(float4*)&attnc[1024 + tid * 4] = s;
    } else if (tid < 56) {
        const int pc = tid - 32;
        float4 s = redV[pc];
        #pragma unroll
        for (int gg = 1; gg < 4; ++gg) {
            float4 v = redV[gg * 24 + pc];
            s.x += v.x; s.y += v.y; s.z += v.z; s.w += v.w;
        }
        *(float4*)&attnc[1152 + pc * 4] = s;
    }
}

// ---------------- Kernel 3: merge chunk partials -> feats ----------------
__global__ __launch_bounds__(256) void k_attn_merge(
    const float* __restrict__ attnp,
    const float* __restrict__ rot, const float* __restrict__ trans,
    float* __restrict__ feats)
{
    const int i = blockIdx.x;
    const int tid = threadIdx.x;
    __shared__ float sm_m[32], sm_l[32], sW[32], sL[8], pts_s[96];

    const float* base = attnp + (size_t)i * 4 * PCH;
    if (tid < 32) {
        int jcx = tid >> 3, h = tid & 7;
        sm_m[jcx * 8 + h] = base[jcx * PCH + 1248 + h];
        sm_l[jcx * 8 + h] = base[jcx * PCH + 1256 + h];
    }
    __syncthreads();
    if (tid < 8) {
        const int h = tid;
        float M = fmaxf(fmaxf(sm_m[h], sm_m[8 + h]), fmaxf(sm_m[16 + h], sm_m[24 + h]));
        float L = 0.f;
        #pragma unroll
        for (int jcx = 0; jcx < 4; ++jcx) {
            float w = __expf(sm_m[jcx * 8 + h] - M);
            L += sm_l[jcx * 8 + h] * w;
            sW[jcx * 8 + h] = w;
        }
        sL[h] = L;
    }
    __syncthreads();

    {   // out_pair
        const int h = tid >> 5, pq = tid & 31;
        float4 s = make_float4(0, 0, 0, 0);
        #pragma unroll
        for (int jcx = 0; jcx < 4; ++jcx) {
            float4 a = *(const float4*)&base[jcx * PCH + h * 128 + pq * 4];
            float w = sW[jcx * 8 + h];
            s.x += a.x * w; s.y += a.y * w; s.z += a.z * w; s.w += a.w * w;
        }
        float inv = 1.f / sL[h];
        s.x *= inv; s.y *= inv; s.z *= inv; s.w *= inv;
        ((float4*)&feats[(size_t)i * 1280 + 256])[tid] = s;
    }
    if (tid < 32) {      // out_s
        const int h = tid >> 2;
        float4 s = make_float4(0, 0, 0, 0);
        #pragma unroll
        for (int jcx = 0; jcx < 4; ++jcx) {
            float4 a = *(const float4*)&base[jcx * PCH + 1024 + tid * 4];
            float w = sW[jcx * 8 + h];
            s.x += a.x * w; s.y += a.y * w; s.z += a.z * w; s.w += a.w * w;
        }
        float inv = 1.f / sL[h];
        s.x *= inv; s.y *= inv; s.z *= inv; s.w *= inv;
        ((float4*)&feats[(size_t)i * 1280])[tid] = s;
    } else if (tid < 56) {   // points
        const int pc = tid - 32;
        const int h = pc / 3;
        float4 s = make_float4(0, 0, 0, 0);
        #pragma unroll
        for (int jcx = 0; jcx < 4; ++jcx) {
            float4 a = *(const float4*)&base[jcx * PCH + 1152 + pc * 4];
            float w = sW[jcx * 8 + h];
            s.x += a.x * w; s.y += a.y * w; s.z += a.z * w; s.w += a.w * w;
        }
        float inv = 1.f / sL[h];
        s.x *= inv; s.y *= inv; s.z *= inv; s.w *= inv;
        ((float4*)pts_s)[pc] = s;
    }
    __syncthreads();

    if (tid < 32) {
        const float* R = &rot[(size_t)i * 9];
        const float* T = &trans[(size_t)i * 3];
        float px = pts_s[tid * 3 + 0] - T[0];
        float py = pts_s[tid * 3 + 1] - T[1];
        float pz = pts_s[tid * 3 + 2] - T[2];
        float n2 = 0.f;
        float* fo = feats + (size_t)i * 1280;
        #pragma unroll
        for (int r = 0; r < 3; ++r) {
            float lr = px * R[r * 3 + 0] + py * R[r * 3 + 1] + pz * R[r * 3 + 2];
            fo[128 + tid * 3 + r] = lr;
            n2 += lr * lr;
        }
        fo[224 + tid] = sqrtf(n2 + 1e-8f);
    }
}

// ---------------- Kernel 5a: final GEMM, split-K, 128x128 tile ----------------
__global__ __launch_bounds__(256) void k_final_gemm(
    const float* __restrict__ feats, const float* __restrict__ Wout,
    float* __restrict__ partial)
{
    const int m0 = blockIdx.x * 128;
    const int n0 = blockIdx.y * 128;
    const int ks = blockIdx.z;
    const int tid = threadIdx.x;
    const int k0 = ks * KPER;
    __shared__ float As[16][132];
    __shared__ float Bs[16][132];
    const int tx = tid & 15, ty = tid >> 4;
    float acc[8][8] = {};

    for (int kt = 0; kt < KPER; kt += 16) {
        #pragma unroll
        for (int it = 0; it < 2; ++it) {
            const int l = tid + it * 256;
            const int row = l >> 2, kq = l & 3;
            float4 a = *(const float4*)&feats[(size_t)(m0 + row) * 1280 + k0 + kt + kq * 4];
            As[kq * 4 + 0][row] = a.x; As[kq * 4 + 1][row] = a.y;
            As[kq * 4 + 2][row] = a.z; As[kq * 4 + 3][row] = a.w;
            const int kk = l >> 5, nq = l & 31;
            float4 b = *(const float4*)&Wout[(size_t)(k0 + kt + kk) * 384 + n0 + nq * 4];
            *(float4*)&Bs[kk][nq * 4] = b;
        }
        __syncthreads();
        #pragma unroll
        for (int k = 0; k < 16; ++k) {
            float4 a0 = *(const float4*)&As[k][ty * 8];
            float4 a1 = *(const float4*)&As[k][ty * 8 + 4];
            float4 b0 = *(const float4*)&Bs[k][tx * 8];
            float4 b1 = *(const float4*)&Bs[k][tx * 8 + 4];
            float am[8] = {a0.x, a0.y, a0.z, a0.w, a1.x, a1.y, a1.z, a1.w};
            float bn[8] = {b0.x, b0.y, b0.z, b0.w, b1.x, b1.y, b1.z, b1.w};
            #pragma unroll
            for (int r = 0; r < 8; ++r)
                #pragma unroll
                for (int c = 0; c < 8; ++c)
                    acc[r][c] += am[r] * bn[c];
        }
        __syncthreads();
    }
    float* po = partial + (size_t)ks * (512 * 384);
    #pragma unroll
    for (int r = 0; r < 8; ++r) {
        *(float4*)&po[(size_t)(m0 + ty * 8 + r) * 384 + n0 + tx * 8]     = *(float4*)&acc[r][0];
        *(float4*)&po[(size_t)(m0 + ty * 8 + r) * 384 + n0 + tx * 8 + 4] = *(float4*)&acc[r][4];
    }
}

// ---------------- Kernel 5b: split-K reduce + bias ----------------
__global__ __launch_bounds__(256) void k_reduce(
    const float* __restrict__ partial, const float* __restrict__ bout,
    float* __restrict__ out)
{
    const int f = blockIdx.x * 256 + threadIdx.x;
    const int e = f * 4;
    const int col = e % 384;
    float4 acc = *(const float4*)&bout[col];
    #pragma unroll
    for (int s = 0; s < KSL; ++s) {
        float4 p = *(const float4*)&partial[(size_t)s * (512 * 384) + e];
        acc.x += p.x; acc.y += p.y; acc.z += p.z; acc.w += p.w;
    }
    *(float4*)&out[e] = acc;
}

extern "C" void kernel_launch(void* const* d_in, const int* in_sizes, int n_in,
                              void* d_out, int out_size, void* d_ws, size_t ws_size,
                              hipStream_t stream) {
    const float* x     = (const float*)d_in[0];
    const float* pair  = (const float*)d_in[1];
    const float* rot   = (const float*)d_in[2];
    const float* trans = (const float*)d_in[3];
    const float* Wsq   = (const float*)d_in[4];
    const float* Wsk   = (const float*)d_in[5];
    const float* Wsv   = (const float*)d_in[6];
    const float* Wpq   = (const float*)d_in[7];
    const float* Wpk   = (const float*)d_in[8];
    const float* Wpv   = (const float*)d_in[9];
    const float* Wpair = (const float*)d_in[10];
    const float* bpair = (const float*)d_in[11];
    const float* pwts  = (const float*)d_in[12];
    const float* Wout  = (const float*)d_in[13];
    const float* bout  = (const float*)d_in[14];

    float* ws    = (float*)d_ws;
    float* qs    = ws;                       // 512*128
    float* ks    = qs + 512 * 128;
    float* vs    = ks + 512 * 128;
    float* qp    = vs + 512 * 128;           // 512*96
    float* kp    = qp + 512 * 96;
    float* vp    = kp + 512 * 96;
    float* feats = vp + 512 * 96;            // 512*1280
    float* scratch = feats + 512 * 1280;
    float* attnp = scratch + 1048576;        // 2048*1264
    float* plq   = attnp + 2048 * PCH;
    float* plk   = plq + 512 * 96;
    float* plv   = plk + 512 * 96;
    float* partial = scratch;                // KSL*512*384 (attnp dead after merge)

    k_proj_gemm<<<dim3(8, 21), 256, 0, stream>>>(x, Wsq, Wsk, Wsv, Wpq, Wpk, Wpv,
                                                 qs, ks, vs, plq, plk, plv);
    k_frames<<<192, 256, 0, stream>>>(plq, plk, plv, rot, trans, qp, kp, vp);
    k_attn<<<dim3(4, 512), 256, 0, stream>>>(pair, qs, ks, qp, kp, vs, vp,
                                             Wpair, bpair, pwts, attnp);
    k_attn_merge<<<512, 256, 0, stream>>>(attnp, rot, trans, feats);
    k_final_gemm<<<dim3(4, 3, KSL), 256, 0, stream>>>(feats, Wout, partial);
    k_reduce<<<192, 256, 0, stream>>>(partial, bout, (float*)d_out);
}

// Round 14
// 111.149 us; speedup vs baseline: 1.5236x; 1.5236x over previous
//
#include <hip/hip_runtime.h>
#include <hip/hip_bf16.h>
#include <math.h>

#define NN 512
#define DIMX 384
#define HH 8
#define PAIRD 128

#define SCALAR_SCALE 0.144337567297406f   // (3*16)^-0.5
#define POINT_SCALE  0.136082763487954f   // (12*4.5)^-0.5
#define PAIR_SCALE   0.577350269189626f   // 3^-0.5

#define KSL 8
#define KPER 160      // 1280 / KSL
#define PCH 1264      // floats per (i, jc) attn partial chunk

// ---------------- Kernel 1a: unified projection GEMM ----------------
__global__ __launch_bounds__(256) void k_proj_gemm(
    const float* __restrict__ x,
    const float* __restrict__ Wsq, const float* __restrict__ Wsk, const float* __restrict__ Wsv,
    const float* __restrict__ Wpq, const float* __restrict__ Wpk, const float* __restrict__ Wpv,
    float* __restrict__ qs, float* __restrict__ ks, float* __restrict__ vs,
    float* __restrict__ plq, float* __restrict__ plk, float* __restrict__ plv)
{
    const int m0 = blockIdx.x * 64;
    const int t  = blockIdx.y;   // 0..20
    int ldw, c0;
    const float* W;
    float* out;
    if (t < 12) {
        const float* Ws[3] = {Wsq, Wsk, Wsv};
        float* outs[3] = {qs, ks, vs};
        W = Ws[t >> 2]; out = outs[t >> 2]; c0 = (t & 3) * 32; ldw = 128;
    } else {
        const int u = t - 12;
        const float* Wp[3] = {Wpq, Wpk, Wpv};
        float* outp[3] = {plq, plk, plv};
        W = Wp[u / 3]; out = outp[u / 3]; c0 = (u % 3) * 32; ldw = 96;
    }
    const int tid = threadIdx.x;
    __shared__ float xs[32][68];
    __shared__ float Bs[32][36];
    const int tx = tid & 15, ty = tid >> 4;
    float acc[4][2] = {};

    for (int kt = 0; kt < DIMX; kt += 32) {
        #pragma unroll
        for (int it = 0; it < 2; ++it) {
            int l = tid + it * 256;
            int row = l >> 3, kq = l & 7;
            float4 a = *(const float4*)&x[(size_t)(m0 + row) * DIMX + kt + kq * 4];
            xs[kq*4+0][row] = a.x; xs[kq*4+1][row] = a.y;
            xs[kq*4+2][row] = a.z; xs[kq*4+3][row] = a.w;
        }
        {
            int kk = tid >> 3, nq = tid & 7;
            float4 b = *(const float4*)&W[(size_t)(kt + kk) * ldw + c0 + nq * 4];
            *(float4*)&Bs[kk][nq * 4] = b;
        }
        __syncthreads();
        #pragma unroll
        for (int k = 0; k < 32; ++k) {
            float4 a  = *(const float4*)&xs[k][ty * 4];
            float2 bv = *(const float2*)&Bs[k][tx * 2];
            acc[0][0] += a.x * bv.x; acc[0][1] += a.x * bv.y;
            acc[1][0] += a.y * bv.x; acc[1][1] += a.y * bv.y;
            acc[2][0] += a.z * bv.x; acc[2][1] += a.z * bv.y;
            acc[3][0] += a.w * bv.x; acc[3][1] += a.w * bv.y;
        }
        __syncthreads();
    }
    #pragma unroll
    for (int r = 0; r < 4; ++r) {
        float2 v = make_float2(acc[r][0], acc[r][1]);
        *(float2*)&out[(size_t)(m0 + ty * 4 + r) * ldw + c0 + tx * 2] = v;
    }
}

// ---------------- Kernel 1b: frame transform ----------------
__global__ __launch_bounds__(256) void k_frames(
    const float* __restrict__ plq, const float* __restrict__ plk, const float* __restrict__ plv,
    const float* __restrict__ rot, const float* __restrict__ trans,
    float* __restrict__ qp, float* __restrict__ kp, float* __restrict__ vp)
{
    int g = blockIdx.x * 256 + threadIdx.x;
    int m = g >> 14;
    int rem = g & 16383;
    int i = rem >> 5;
    int p = rem & 31;
    const float* pl = (m == 0 ? plq : (m == 1 ? plk : plv));
    float*       o  = (m == 0 ? qp  : (m == 1 ? kp  : vp));
    const float* l = &pl[(size_t)i * 96 + p * 3];
    const float* R = &rot[(size_t)i * 9];
    const float* T = &trans[(size_t)i * 3];
    float l0 = l[0], l1 = l[1], l2 = l[2];
    float* op = o + (size_t)i * 96 + p * 3;
    #pragma unroll
    for (int c = 0; c < 3; ++c)
        op[c] = l0 * R[0 * 3 + c] + l1 * R[1 * 3 + c] + l2 * R[2 * 3 + c] + T[c];
}

// ---------------- Kernel 2: fused attention ----------------
// block = (jc, i). Phase 0: chunk bias GEMV (register butterfly) -> LDS (pair's
// one cold HBM read). Phase 1: 128 logits -> LDS. Phase 2: one softmax.
// Phase 3: j-split accumulation (unroll 2 — VGPR 52, Occ 38%; proven best r11).
__global__ __launch_bounds__(256) void k_attn(
    const float* __restrict__ pair,
    const float* __restrict__ qs, const float* __restrict__ ks,
    const float* __restrict__ qp, const float* __restrict__ kp,
    const float* __restrict__ vs, const float* __restrict__ vp,
    const float* __restrict__ Wpair, const float* __restrict__ bpair,
    const float* __restrict__ pwts,
    float* __restrict__ attnp)
{
    const int jc  = blockIdx.x;      // 0..3
    const int i   = blockIdx.y;      // 0..511
    const int tid = threadIdx.x;

    __shared__ float smem[4992];     // ~20 KB; lg/bias_s aliased by reduce tail
    float* lg     = smem;            // [8][132] raw logits -> weights
    float* qs_s   = smem + 1056;     // [128]
    float* qp_s   = smem + 1184;     // [96]
    float* bias_s = smem + 1280;     // [8][132] chunk pair-bias

    if (tid < 32) ((float4*)qs_s)[tid] = ((const float4*)(qs + (size_t)i * 128))[tid];
    if (tid < 24) ((float4*)qp_s)[tid] = ((const float4*)(qp + (size_t)i * 96))[tid];

    // ---- Phase 0: bias GEMV for this chunk's 128 rows (pair cold read) ----
    {
        const int b  = tid >> 5;     // row group 0..7
        const int pq = tid & 31;     // p-slice (float4 index)
        float wv[32];
        {
            const float4* W4 = (const float4*)(Wpair + pq * 32);
            #pragma unroll
            for (int q = 0; q < 8; ++q) {
                float4 w = W4[q];
                wv[q * 4 + 0] = w.x; wv[q * 4 + 1] = w.y;
                wv[q * 4 + 2] = w.z; wv[q * 4 + 3] = w.w;
            }
        }
        #pragma unroll
        for (int it = 0; it < 4; ++it) {
            const int j0 = it * 32;
            float cur[32];           // [r 4][h 8] partials
            #pragma unroll
            for (int r = 0; r < 4; ++r) {
                const int j = jc * 128 + j0 + b + r * 8;
                float4 a = *(const float4*)&pair[((size_t)i * NN + j) * PAIRD + pq * 4];
                float ac[4] = {a.x, a.y, a.z, a.w};
                #pragma unroll
                for (int h = 0; h < 8; ++h) {
                    float s = 0.f;
                    #pragma unroll
                    for (int p = 0; p < 4; ++p) s += ac[p] * wv[p * 8 + h];
                    cur[r * 8 + h] = s;
                }
            }
            #pragma unroll
            for (int s5 = 0; s5 < 5; ++s5) {
                const int m = 16 >> s5;
                const bool up = (pq & m) != 0;
                #pragma unroll
                for (int u = 0; u < (16 >> s5); ++u) {
                    float lo = cur[u], hi = cur[u + (16 >> s5)];
                    float send = up ? lo : hi;
                    float got  = __shfl_xor(send, m);
                    cur[u] = up ? (hi + got) : (lo + got);
                }
            }
            bias_s[(pq & 7) * 132 + (j0 + b + (pq >> 3) * 8)] = cur[0];
        }
    }
    __syncthreads();

    const int g   = tid & 7;         // phase 1: head
    const int jjL = tid >> 3;        // phase 1: j-lane (0..31)
    const int h2  = tid >> 5;        // phase 2: head / phase 3: j-group
    const int jj2 = tid & 31;        // phase 2: j-lane / phase 3: float4 channel
    const int jg  = h2, pq = jj2;

    // ---- Phase 1: 4 independent logits per thread ----
    {
        const float bp_h = bpair[g];
        const float pw_h = log1pf(__expf(pwts[g]));
        const float4* qr4 = (const float4*)&qs_s[g * 16];
        const float4* qp4 = (const float4*)&qp_s[g * 12];
        #pragma unroll
        for (int t = 0; t < 4; ++t) {
            const int jl = t * 32 + jjL;
            const int j  = jc * 128 + jl;
            float bv = bias_s[g * 132 + jl];
            float sc = 0.f;
            const float4* kr4 = (const float4*)(ks + (size_t)j * 128 + g * 16);
            #pragma unroll
            for (int q = 0; q < 4; ++q) {
                float4 kq = kr4[q], qq = qr4[q];
                sc += qq.x * kq.x + qq.y * kq.y + qq.z * kq.z + qq.w * kq.w;
            }
            float d2 = 0.f;
            const float4* kp4 = (const float4*)(kp + (size_t)j * 96 + g * 12);
            #pragma unroll
            for (int q = 0; q < 3; ++q) {
                float4 kq = kp4[q], qq = qp4[q];
                float dx = qq.x - kq.x, dy = qq.y - kq.y, dz = qq.z - kq.z, dw = qq.w - kq.w;
                d2 += dx * dx + dy * dy + dz * dz + dw * dw;
            }
            lg[g * 132 + jl] = sc * SCALAR_SCALE + (bv + bp_h) * PAIR_SCALE
                             - 0.5f * POINT_SCALE * pw_h * d2;
        }
    }
    __syncthreads();

    // ---- Phase 2: one softmax per head row (32 lanes each) ----
    float m_run, l_run;
    {
        float v0 = lg[h2 * 132 + jj2],      v1 = lg[h2 * 132 + 32 + jj2];
        float v2 = lg[h2 * 132 + 64 + jj2], v3 = lg[h2 * 132 + 96 + jj2];
        float m = fmaxf(fmaxf(v0, v1), fmaxf(v2, v3));
        #pragma unroll
        for (int off = 16; off > 0; off >>= 1) m = fmaxf(m, __shfl_xor(m, off));
        float e0 = __expf(v0 - m), e1 = __expf(v1 - m);
        float e2 = __expf(v2 - m), e3 = __expf(v3 - m);
        float s = e0 + e1 + e2 + e3;
        #pragma unroll
        for (int off = 16; off > 0; off >>= 1) s += __shfl_xor(s, off);
        m_run = m; l_run = s;
        lg[h2 * 132 + jj2]      = e0; lg[h2 * 132 + 32 + jj2] = e1;
        lg[h2 * 132 + 64 + jj2] = e2; lg[h2 * 132 + 96 + jj2] = e3;
    }
    __syncthreads();

    // ---- Phase 3: j-split accumulation, unroll 2 ----
    float4 accP[8];
    #pragma unroll
    for (int z = 0; z < 8; ++z) accP[z] = make_float4(0, 0, 0, 0);
    float4 accS = make_float4(0, 0, 0, 0);
    float4 accV = make_float4(0, 0, 0, 0);
    {
        const float4* pair4 = (const float4*)pair;
        const float4* vs4   = (const float4*)vs;
        const float4* vp4   = (const float4*)vp;
        #pragma unroll 2
        for (int jo = 0; jo < 16; ++jo) {
            const int jl = jo * 8 + jg;
            const int jglob = jc * 128 + jl;
            float4 pr = pair4[((size_t)i * NN + jglob) * 32 + pq];
            #pragma unroll
            for (int z = 0; z < 8; ++z) {
                float a = lg[z * 132 + jl];
                accP[z].x += a * pr.x; accP[z].y += a * pr.y;
                accP[z].z += a * pr.z; accP[z].w += a * pr.w;
            }
            {
                float a = lg[(pq >> 2) * 132 + jl];
                float4 v = vs4[(size_t)jglob * 32 + pq];
                accS.x += a * v.x; accS.y += a * v.y; accS.z += a * v.z; accS.w += a * v.w;
            }
            if (pq < 24) {
                float a = lg[(pq / 3) * 132 + jl];
                float4 v = vp4[(size_t)jglob * 24 + pq];
                accV.x += a * v.x; accV.y += a * v.y; accV.z += a * v.z; accV.w += a * v.w;
            }
        }
    }
    __syncthreads();                                  // lg/bias_s dead; safe to alias

    float* attnc = attnp + ((size_t)i * 4 + jc) * PCH;
    if (jj2 == 0) { attnc[1248 + h2] = m_run; attnc[1256 + h2] = l_run; }

    // cross-wave combine: xor-32, then 4 group-pairs via LDS
    #pragma unroll
    for (int z = 0; z < 8; ++z) {
        accP[z].x += __shfl_xor(accP[z].x, 32); accP[z].y += __shfl_xor(accP[z].y, 32);
        accP[z].z += __shfl_xor(accP[z].z, 32); accP[z].w += __shfl_xor(accP[z].w, 32);
    }
    accS.x += __shfl_xor(accS.x, 32); accS.y += __shfl_xor(accS.y, 32);
    accS.z += __shfl_xor(accS.z, 32); accS.w += __shfl_xor(accS.w, 32);
    accV.x += __shfl_xor(accV.x, 32); accV.y += __shfl_xor(accV.y, 32);
    accV.z += __shfl_xor(accV.z, 32); accV.w += __shfl_xor(accV.w, 32);

    float4* redP = (float4*)smem;               // [4][8][32]
    float4* redS = (float4*)(smem + 4096);      // [4][32]
    float4* redV = (float4*)(smem + 4608);      // [4][24]
    const int jgp = jg >> 1;
    if ((jg & 1) == 0) {
        #pragma unroll
        for (int z = 0; z < 8; ++z) redP[(jgp * 8 + z) * 32 + pq] = accP[z];
        redS[jgp * 32 + pq] = accS;
        if (pq < 24) redV[jgp * 24 + pq] = accV;
    }
    __syncthreads();

    {
        const int z = tid >> 5, p4 = tid & 31;
        float4 s = redP[z * 32 + p4];
        #pragma unroll
        for (int gg = 1; gg < 4; ++gg) {
            float4 v = redP[(gg * 8 + z) * 32 + p4];
            s.x += v.x; s.y += v.y; s.z += v.z; s.w += v.w;
        }
        *(float4*)&attnc[z * 128 + p4 * 4] = s;
    }
    if (tid < 32) {
        float4 s = redS[tid];
        #pragma unroll
        for (int gg = 1; gg < 4; ++gg) {
            float4 v = redS[gg * 32 + tid];
            s.x += v.x; s.y += v.y; s.z += v.z; s.w += v.w;
        }
        *(float4*)&attnc[1024 + tid * 4] = s;
    } else if (tid < 56) {
        const int pc = tid - 32;
        float4 s = redV[pc];
        #pragma unroll
        for (int gg = 1; gg < 4; ++gg) {
            float4 v = redV[gg * 24 + pc];
            s.x += v.x; s.y += v.y; s.z += v.z; s.w += v.w;
        }
        *(float4*)&attnc[1152 + pc * 4] = s;
    }
}

// ---------------- Kernel 3: merge chunk partials -> feats ----------------
__global__ __launch_bounds__(256) void k_attn_merge(
    const float* __restrict__ attnp,
    const float* __restrict__ rot, const float* __restrict__ trans,
    float* __restrict__ feats)
{
    const int i = blockIdx.x;
    const int tid = threadIdx.x;
    __shared__ float sm_m[32], sm_l[32], sW[32], sL[8], pts_s[96];

    const float* base = attnp + (size_t)i * 4 * PCH;
    if (tid < 32) {
        int jcx = tid >> 3, h = tid & 7;
        sm_m[jcx * 8 + h] = base[jcx * PCH + 1248 + h];
        sm_l[jcx * 8 + h] = base[jcx * PCH + 1256 + h];
    }
    __syncthreads();
    if (tid < 8) {
        const int h = tid;
        float M = fmaxf(fmaxf(sm_m[h], sm_m[8 + h]), fmaxf(sm_m[16 + h], sm_m[24 + h]));
        float L = 0.f;
        #pragma unroll
        for (int jcx = 0; jcx < 4; ++jcx) {
            float w = __expf(sm_m[jcx * 8 + h] - M);
            L += sm_l[jcx * 8 + h] * w;
            sW[jcx * 8 + h] = w;
        }
        sL[h] = L;
    }
    __syncthreads();

    {   // out_pair
        const int h = tid >> 5, pq = tid & 31;
        float4 s = make_float4(0, 0, 0, 0);
        #pragma unroll
        for (int jcx = 0; jcx < 4; ++jcx) {
            float4 a = *(const float4*)&base[jcx * PCH + h * 128 + pq * 4];
            float w = sW[jcx * 8 + h];
            s.x += a.x * w; s.y += a.y * w; s.z += a.z * w; s.w += a.w * w;
        }
        float inv = 1.f / sL[h];
        s.x *= inv; s.y *= inv; s.z *= inv; s.w *= inv;
        ((float4*)&feats[(size_t)i * 1280 + 256])[tid] = s;
    }
    if (tid < 32) {      // out_s
        const int h = tid >> 2;
        float4 s = make_float4(0, 0, 0, 0);
        #pragma unroll
        for (int jcx = 0; jcx < 4; ++jcx) {
            float4 a = *(const float4*)&base[jcx * PCH + 1024 + tid * 4];
            float w = sW[jcx * 8 + h];
            s.x += a.x * w; s.y += a.y * w; s.z += a.z * w; s.w += a.w * w;
        }
        float inv = 1.f / sL[h];
        s.x *= inv; s.y *= inv; s.z *= inv; s.w *= inv;
        ((float4*)&feats[(size_t)i * 1280])[tid] = s;
    } else if (tid < 56) {   // points
        const int pc = tid - 32;
        const int h = pc / 3;
        float4 s = make_float4(0, 0, 0, 0);
        #pragma unroll
        for (int jcx = 0; jcx < 4; ++jcx) {
            float4 a = *(const float4*)&base[jcx * PCH + 1152 + pc * 4];
            float w = sW[jcx * 8 + h];
            s.x += a.x * w; s.y += a.y * w; s.z += a.z * w; s.w += a.w * w;
        }
        float inv = 1.f / sL[h];
        s.x *= inv; s.y *= inv; s.z *= inv; s.w *= inv;
        ((float4*)pts_s)[pc] = s;
    }
    __syncthreads();

    if (tid < 32) {
        const float* R = &rot[(size_t)i * 9];
        const float* T = &trans[(size_t)i * 3];
        float px = pts_s[tid * 3 + 0] - T[0];
        float py = pts_s[tid * 3 + 1] - T[1];
        float pz = pts_s[tid * 3 + 2] - T[2];
        float n2 = 0.f;
        float* fo = feats + (size_t)i * 1280;
        #pragma unroll
        for (int r = 0; r < 3; ++r) {
            float lr = px * R[r * 3 + 0] + py * R[r * 3 + 1] + pz * R[r * 3 + 2];
            fo[128 + tid * 3 + r] = lr;
            n2 += lr * lr;
        }
        fo[224 + tid] = sqrtf(n2 + 1e-8f);
    }
}

// ---------------- Kernel 5a: final GEMM, split-K, 128x128 tile ----------------
__global__ __launch_bounds__(256) void k_final_gemm(
    const float* __restrict__ feats, const float* __restrict__ Wout,
    float* __restrict__ partial)
{
    const int m0 = blockIdx.x * 128;
    const int n0 = blockIdx.y * 128;
    const int ks = blockIdx.z;
    const int tid = threadIdx.x;
    const int k0 = ks * KPER;
    __shared__ float As[16][132];
    __shared__ float Bs[16][132];
    const int tx = tid & 15, ty = tid >> 4;
    float acc[8][8] = {};

    for (int kt = 0; kt < KPER; kt += 16) {
        #pragma unroll
        for (int it = 0; it < 2; ++it) {
            const int l = tid + it * 256;
            const int row = l >> 2, kq = l & 3;
            float4 a = *(const float4*)&feats[(size_t)(m0 + row) * 1280 + k0 + kt + kq * 4];
            As[kq * 4 + 0][row] = a.x; As[kq * 4 + 1][row] = a.y;
            As[kq * 4 + 2][row] = a.z; As[kq * 4 + 3][row] = a.w;
            const int kk = l >> 5, nq = l & 31;
            float4 b = *(const float4*)&Wout[(size_t)(k0 + kt + kk) * 384 + n0 + nq * 4];
            *(float4*)&Bs[kk][nq * 4] = b;
        }
        __syncthreads();
        #pragma unroll
        for (int k = 0; k < 16; ++k) {
            float4 a0 = *(const float4*)&As[k][ty * 8];
            float4 a1 = *(const float4*)&As[k][ty * 8 + 4];
            float4 b0 = *(const float4*)&Bs[k][tx * 8];
            float4 b1 = *(const float4*)&Bs[k][tx * 8 + 4];
            float am[8] = {a0.x, a0.y, a0.z, a0.w, a1.x, a1.y, a1.z, a1.w};
            float bn[8] = {b0.x, b0.y, b0.z, b0.w, b1.x, b1.y, b1.z, b1.w};
            #pragma unroll
            for (int r = 0; r < 8; ++r)
                #pragma unroll
                for (int c = 0; c < 8; ++c)
                    acc[r][c] += am[r] * bn[c];
        }
        __syncthreads();
    }
    float* po = partial + (size_t)ks * (512 * 384);
    #pragma unroll
    for (int r = 0; r < 8; ++r) {
        *(float4*)&po[(size_t)(m0 + ty * 8 + r) * 384 + n0 + tx * 8]     = *(float4*)&acc[r][0];
        *(float4*)&po[(size_t)(m0 + ty * 8 + r) * 384 + n0 + tx * 8 + 4] = *(float4*)&acc[r][4];
    }
}

// ---------------- Kernel 5b: split-K reduce + bias ----------------
__global__ __launch_bounds__(256) void k_reduce(
    const float* __restrict__ partial, const float* __restrict__ bout,
    float* __restrict__ out)
{
    const int f = blockIdx.x * 256 + threadIdx.x;
    const int e = f * 4;
    const int col = e % 384;
    float4 acc = *(const float4*)&bout[col];
    #pragma unroll
    for (int s = 0; s < KSL; ++s) {
        float4 p = *(const float4*)&partial[(size_t)s * (512 * 384) + e];
        acc.x += p.x; acc.y += p.y; acc.z += p.z; acc.w += p.w;
    }
    *(float4*)&out[e] = acc;
}

extern "C" void kernel_launch(void* const* d_in, const int* in_sizes, int n_in,
                              void* d_out, int out_size, void* d_ws, size_t ws_size,
                              hipStream_t stream) {
    const float* x     = (const float*)d_in[0];
    const float* pair  = (const float*)d_in[1];
    const float* rot   = (const float*)d_in[2];
    const float* trans = (const float*)d_in[3];
    const float* Wsq   = (const float*)d_in[4];
    const float* Wsk   = (const float*)d_in[5];
    const float* Wsv   = (const float*)d_in[6];
    const float* Wpq   = (const float*)d_in[7];
    const float* Wpk   = (const float*)d_in[8];
    const float* Wpv   = (const float*)d_in[9];
    const float* Wpair = (const float*)d_in[10];
    const float* bpair = (const float*)d_in[11];
    const float* pwts  = (const float*)d_in[12];
    const float* Wout  = (const float*)d_in[13];
    const float* bout  = (const float*)d_in[14];

    float* ws    = (float*)d_ws;
    float* qs    = ws;                       // 512*128
    float* ks    = qs + 512 * 128;
    float* vs    = ks + 512 * 128;
    float* qp    = vs + 512 * 128;           // 512*96
    float* kp    = qp + 512 * 96;
    float* vp    = kp + 512 * 96;
    float* feats = vp + 512 * 96;            // 512*1280
    float* scratch = feats + 512 * 1280;
    float* attnp = scratch + 1048576;        // 2048*1264
    float* plq   = attnp + 2048 * PCH;
    float* plk   = plq + 512 * 96;
    float* plv   = plk + 512 * 96;
    float* partial = scratch;                // KSL*512*384 (attnp dead after merge)

    k_proj_gemm<<<dim3(8, 21), 256, 0, stream>>>(x, Wsq, Wsk, Wsv, Wpq, Wpk, Wpv,
                                                 qs, ks, vs, plq, plk, plv);
    k_frames<<<192, 256, 0, stream>>>(plq, plk, plv, rot, trans, qp, kp, vp);
    k_attn<<<dim3(4, 512), 256, 0, stream>>>(pair, qs, ks, qp, kp, vs, vp,
                                             Wpair, bpair, pwts, attnp);
    k_attn_merge<<<512, 256, 0, stream>>>(attnp, rot, trans, feats);
    k_final_gemm<<<dim3(4, 3, KSL), 256, 0, stream>>>(feats, Wout, partial);
    k_reduce<<<192, 256, 0, stream>>>(partial, bout, (float*)d_out);
}

// Round 15
// 110.910 us; speedup vs baseline: 1.5269x; 1.0022x over previous
//
#include <hip/hip_runtime.h>
#include <hip/hip_bf16.h>
#include <math.h>

#define NN 512
#define DIMX 384
#define HH 8
#define PAIRD 128

#define SCALAR_SCALE 0.144337567297406f   // (3*16)^-0.5
#define POINT_SCALE  0.136082763487954f   // (12*4.5)^-0.5
#define PAIR_SCALE   0.577350269189626f   // 3^-0.5

#define KSL 8
#define KPER 160      // 1280 / KSL
#define PCH 1264      // floats per (i, jc) attn partial chunk

// ---------------- Kernel 1a: unified projection GEMM ----------------
__global__ __launch_bounds__(256) void k_proj_gemm(
    const float* __restrict__ x,
    const float* __restrict__ Wsq, const float* __restrict__ Wsk, const float* __restrict__ Wsv,
    const float* __restrict__ Wpq, const float* __restrict__ Wpk, const float* __restrict__ Wpv,
    float* __restrict__ qs, float* __restrict__ ks, float* __restrict__ vs,
    float* __restrict__ plq, float* __restrict__ plk, float* __restrict__ plv)
{
    const int m0 = blockIdx.x * 64;
    const int t  = blockIdx.y;   // 0..20
    int ldw, c0;
    const float* W;
    float* out;
    if (t < 12) {
        const float* Ws[3] = {Wsq, Wsk, Wsv};
        float* outs[3] = {qs, ks, vs};
        W = Ws[t >> 2]; out = outs[t >> 2]; c0 = (t & 3) * 32; ldw = 128;
    } else {
        const int u = t - 12;
        const float* Wp[3] = {Wpq, Wpk, Wpv};
        float* outp[3] = {plq, plk, plv};
        W = Wp[u / 3]; out = outp[u / 3]; c0 = (u % 3) * 32; ldw = 96;
    }
    const int tid = threadIdx.x;
    __shared__ float xs[32][68];
    __shared__ float Bs[32][36];
    const int tx = tid & 15, ty = tid >> 4;
    float acc[4][2] = {};

    for (int kt = 0; kt < DIMX; kt += 32) {
        #pragma unroll
        for (int it = 0; it < 2; ++it) {
            int l = tid + it * 256;
            int row = l >> 3, kq = l & 7;
            float4 a = *(const float4*)&x[(size_t)(m0 + row) * DIMX + kt + kq * 4];
            xs[kq*4+0][row] = a.x; xs[kq*4+1][row] = a.y;
            xs[kq*4+2][row] = a.z; xs[kq*4+3][row] = a.w;
        }
        {
            int kk = tid >> 3, nq = tid & 7;
            float4 b = *(const float4*)&W[(size_t)(kt + kk) * ldw + c0 + nq * 4];
            *(float4*)&Bs[kk][nq * 4] = b;
        }
        __syncthreads();
        #pragma unroll
        for (int k = 0; k < 32; ++k) {
            float4 a  = *(const float4*)&xs[k][ty * 4];
            float2 bv = *(const float2*)&Bs[k][tx * 2];
            acc[0][0] += a.x * bv.x; acc[0][1] += a.x * bv.y;
            acc[1][0] += a.y * bv.x; acc[1][1] += a.y * bv.y;
            acc[2][0] += a.z * bv.x; acc[2][1] += a.z * bv.y;
            acc[3][0] += a.w * bv.x; acc[3][1] += a.w * bv.y;
        }
        __syncthreads();
    }
    #pragma unroll
    for (int r = 0; r < 4; ++r) {
        float2 v = make_float2(acc[r][0], acc[r][1]);
        *(float2*)&out[(size_t)(m0 + ty * 4 + r) * ldw + c0 + tx * 2] = v;
    }
}

// ---------------- Kernel 1b: frame transform ----------------
__global__ __launch_bounds__(256) void k_frames(
    const float* __restrict__ plq, const float* __restrict__ plk, const float* __restrict__ plv,
    const float* __restrict__ rot, const float* __restrict__ trans,
    float* __restrict__ qp, float* __restrict__ kp, float* __restrict__ vp)
{
    int g = blockIdx.x * 256 + threadIdx.x;
    int m = g >> 14;
    int rem = g & 16383;
    int i = rem >> 5;
    int p = rem & 31;
    const float* pl = (m == 0 ? plq : (m == 1 ? plk : plv));
    float*       o  = (m == 0 ? qp  : (m == 1 ? kp  : vp));
    const float* l = &pl[(size_t)i * 96 + p * 3];
    const float* R = &rot[(size_t)i * 9];
    const float* T = &trans[(size_t)i * 3];
    float l0 = l[0], l1 = l[1], l2 = l[2];
    float* op = o + (size_t)i * 96 + p * 3;
    #pragma unroll
    for (int c = 0; c < 3; ++c)
        op[c] = l0 * R[0 * 3 + c] + l1 * R[1 * 3 + c] + l2 * R[2 * 3 + c] + T[c];
}

// ---------------- Kernel 2: fused attention ----------------
// block = (jc, i). Phase 0: chunk bias GEMV (register butterfly) -> LDS (pair's
// one cold HBM read). Phase 1: 128 logits -> LDS in [j][8] layout (linear,
// conflict-free writes). Phase 2: one softmax. Phase 3: j-split accumulation;
// per-iter LDS = 2 broadcast ds_read_b128 + 2 scalar reads (was 10 scalar).
__global__ __launch_bounds__(256) void k_attn(
    const float* __restrict__ pair,
    const float* __restrict__ qs, const float* __restrict__ ks,
    const float* __restrict__ qp, const float* __restrict__ kp,
    const float* __restrict__ vs, const float* __restrict__ vp,
    const float* __restrict__ Wpair, const float* __restrict__ bpair,
    const float* __restrict__ pwts,
    float* __restrict__ attnp)
{
    const int jc  = blockIdx.x;      // 0..3
    const int i   = blockIdx.y;      // 0..511
    const int tid = threadIdx.x;

    __shared__ float smem[4992];     // ~20 KB; lg/bias_s aliased by reduce tail
    float* lg     = smem;            // [128][8] logits -> weights (j-major)
    float* qs_s   = smem + 1056;     // [128]
    float* qp_s   = smem + 1184;     // [96]
    float* bias_s = smem + 1280;     // [8][132] chunk pair-bias

    if (tid < 32) ((float4*)qs_s)[tid] = ((const float4*)(qs + (size_t)i * 128))[tid];
    if (tid < 24) ((float4*)qp_s)[tid] = ((const float4*)(qp + (size_t)i * 96))[tid];

    // ---- Phase 0: bias GEMV for this chunk's 128 rows (pair cold read) ----
    {
        const int b  = tid >> 5;     // row group 0..7
        const int pq = tid & 31;     // p-slice (float4 index)
        float wv[32];
        {
            const float4* W4 = (const float4*)(Wpair + pq * 32);
            #pragma unroll
            for (int q = 0; q < 8; ++q) {
                float4 w = W4[q];
                wv[q * 4 + 0] = w.x; wv[q * 4 + 1] = w.y;
                wv[q * 4 + 2] = w.z; wv[q * 4 + 3] = w.w;
            }
        }
        #pragma unroll
        for (int it = 0; it < 4; ++it) {
            const int j0 = it * 32;
            float cur[32];           // [r 4][h 8] partials
            #pragma unroll
            for (int r = 0; r < 4; ++r) {
                const int j = jc * 128 + j0 + b + r * 8;
                float4 a = *(const float4*)&pair[((size_t)i * NN + j) * PAIRD + pq * 4];
                float ac[4] = {a.x, a.y, a.z, a.w};
                #pragma unroll
                for (int h = 0; h < 8; ++h) {
                    float s = 0.f;
                    #pragma unroll
                    for (int p = 0; p < 4; ++p) s += ac[p] * wv[p * 8 + h];
                    cur[r * 8 + h] = s;
                }
            }
            #pragma unroll
            for (int s5 = 0; s5 < 5; ++s5) {
                const int m = 16 >> s5;
                const bool up = (pq & m) != 0;
                #pragma unroll
                for (int u = 0; u < (16 >> s5); ++u) {
                    float lo = cur[u], hi = cur[u + (16 >> s5)];
                    float send = up ? lo : hi;
                    float got  = __shfl_xor(send, m);
                    cur[u] = up ? (hi + got) : (lo + got);
                }
            }
            bias_s[(pq & 7) * 132 + (j0 + b + (pq >> 3) * 8)] = cur[0];
        }
    }
    __syncthreads();

    const int g   = tid & 7;         // phase 1: head
    const int jjL = tid >> 3;        // phase 1: j-lane (0..31)
    const int h2  = tid >> 5;        // phase 2: head / phase 3: j-group
    const int jj2 = tid & 31;        // phase 2: j-lane / phase 3: float4 channel
    const int jg  = h2, pq = jj2;

    // ---- Phase 1: 4 independent logits per thread; lg[j][h] linear writes ----
    {
        const float bp_h = bpair[g];
        const float pw_h = log1pf(__expf(pwts[g]));
        const float4* qr4 = (const float4*)&qs_s[g * 16];
        const float4* qp4 = (const float4*)&qp_s[g * 12];
        #pragma unroll
        for (int t = 0; t < 4; ++t) {
            const int jl = t * 32 + jjL;
            const int j  = jc * 128 + jl;
            float bv = bias_s[g * 132 + jl];
            float sc = 0.f;
            const float4* kr4 = (const float4*)(ks + (size_t)j * 128 + g * 16);
            #pragma unroll
            for (int q = 0; q < 4; ++q) {
                float4 kq = kr4[q], qq = qr4[q];
                sc += qq.x * kq.x + qq.y * kq.y + qq.z * kq.z + qq.w * kq.w;
            }
            float d2 = 0.f;
            const float4* kp4 = (const float4*)(kp + (size_t)j * 96 + g * 12);
            #pragma unroll
            for (int q = 0; q < 3; ++q) {
                float4 kq = kp4[q], qq = qp4[q];
                float dx = qq.x - kq.x, dy = qq.y - kq.y, dz = qq.z - kq.z, dw = qq.w - kq.w;
                d2 += dx * dx + dy * dy + dz * dz + dw * dw;
            }
            lg[jl * 8 + g] = sc * SCALAR_SCALE + (bv + bp_h) * PAIR_SCALE
                           - 0.5f * POINT_SCALE * pw_h * d2;
        }
    }
    __syncthreads();

    // ---- Phase 2: one softmax per head row (32 lanes each) ----
    float m_run, l_run;
    {
        float v0 = lg[(jj2      ) * 8 + h2], v1 = lg[(jj2 + 32) * 8 + h2];
        float v2 = lg[(jj2 +  64) * 8 + h2], v3 = lg[(jj2 + 96) * 8 + h2];
        float m = fmaxf(fmaxf(v0, v1), fmaxf(v2, v3));
        #pragma unroll
        for (int off = 16; off > 0; off >>= 1) m = fmaxf(m, __shfl_xor(m, off));
        float e0 = __expf(v0 - m), e1 = __expf(v1 - m);
        float e2 = __expf(v2 - m), e3 = __expf(v3 - m);
        float s = e0 + e1 + e2 + e3;
        #pragma unroll
        for (int off = 16; off > 0; off >>= 1) s += __shfl_xor(s, off);
        m_run = m; l_run = s;
        lg[(jj2      ) * 8 + h2] = e0; lg[(jj2 + 32) * 8 + h2] = e1;
        lg[(jj2 +  64) * 8 + h2] = e2; lg[(jj2 + 96) * 8 + h2] = e3;
    }
    __syncthreads();

    // ---- Phase 3: j-split accumulation, unroll 2; weights via 2x b128 bcast ----
    float4 accP[8];
    #pragma unroll
    for (int z = 0; z < 8; ++z) accP[z] = make_float4(0, 0, 0, 0);
    float4 accS = make_float4(0, 0, 0, 0);
    float4 accV = make_float4(0, 0, 0, 0);
    {
        const float4* pair4 = (const float4*)pair;
        const float4* vs4   = (const float4*)vs;
        const float4* vp4   = (const float4*)vp;
        #pragma unroll 2
        for (int jo = 0; jo < 16; ++jo) {
            const int jl = jo * 8 + jg;
            const int jglob = jc * 128 + jl;
            float4 pr = pair4[((size_t)i * NN + jglob) * 32 + pq];
            float4 la = *(const float4*)&lg[jl * 8];
            float4 lb = *(const float4*)&lg[jl * 8 + 4];
            float az[8] = {la.x, la.y, la.z, la.w, lb.x, lb.y, lb.z, lb.w};
            #pragma unroll
            for (int z = 0; z < 8; ++z) {
                accP[z].x += az[z] * pr.x; accP[z].y += az[z] * pr.y;
                accP[z].z += az[z] * pr.z; accP[z].w += az[z] * pr.w;
            }
            {
                float a = lg[jl * 8 + (pq >> 2)];
                float4 v = vs4[(size_t)jglob * 32 + pq];
                accS.x += a * v.x; accS.y += a * v.y; accS.z += a * v.z; accS.w += a * v.w;
            }
            if (pq < 24) {
                float a = lg[jl * 8 + (pq / 3)];
                float4 v = vp4[(size_t)jglob * 24 + pq];
                accV.x += a * v.x; accV.y += a * v.y; accV.z += a * v.z; accV.w += a * v.w;
            }
        }
    }
    __syncthreads();                                  // lg/bias_s dead; safe to alias

    float* attnc = attnp + ((size_t)i * 4 + jc) * PCH;
    if (jj2 == 0) { attnc[1248 + h2] = m_run; attnc[1256 + h2] = l_run; }

    // cross-wave combine: xor-32, then 4 group-pairs via LDS
    #pragma unroll
    for (int z = 0; z < 8; ++z) {
        accP[z].x += __shfl_xor(accP[z].x, 32); accP[z].y += __shfl_xor(accP[z].y, 32);
        accP[z].z += __shfl_xor(accP[z].z, 32); accP[z].w += __shfl_xor(accP[z].w, 32);
    }
    accS.x += __shfl_xor(accS.x, 32); accS.y += __shfl_xor(accS.y, 32);
    accS.z += __shfl_xor(accS.z, 32); accS.w += __shfl_xor(accS.w, 32);
    accV.x += __shfl_xor(accV.x, 32); accV.y += __shfl_xor(accV.y, 32);
    accV.z += __shfl_xor(accV.z, 32); accV.w += __shfl_xor(accV.w, 32);

    float4* redP = (float4*)smem;               // [4][8][32]
    float4* redS = (float4*)(smem + 4096);      // [4][32]
    float4* redV = (float4*)(smem + 4608);      // [4][24]
    const int jgp = jg >> 1;
    if ((jg & 1) == 0) {
        #pragma unroll
        for (int z = 0; z < 8; ++z) redP[(jgp * 8 + z) * 32 + pq] = accP[z];
        redS[jgp * 32 + pq] = accS;
        if (pq < 24) redV[jgp * 24 + pq] = accV;
    }
    __syncthreads();

    {
        const int z = tid >> 5, p4 = tid & 31;
        float4 s = redP[z * 32 + p4];
        #pragma unroll
        for (int gg = 1; gg < 4; ++gg) {
            float4 v = redP[(gg * 8 + z) * 32 + p4];
            s.x += v.x; s.y += v.y; s.z += v.z; s.w += v.w;
        }
        *(float4*)&attnc[z * 128 + p4 * 4] = s;
    }
    if (tid < 32) {
        float4 s = redS[tid];
        #pragma unroll
        for (int gg = 1; gg < 4; ++gg) {
            float4 v = redS[gg * 32 + tid];
            s.x += v.x; s.y += v.y; s.z += v.z; s.w += v.w;
        }
        *(float4*)&attnc[1024 + tid * 4] = s;
    } else if (tid < 56) {
        const int pc = tid - 32;
        float4 s = redV[pc];
        #pragma unroll
        for (int gg = 1; gg < 4; ++gg) {
            float4 v = redV[gg * 24 + pc];
            s.x += v.x; s.y += v.y; s.z += v.z; s.w += v.w;
        }
        *(float4*)&attnc[1152 + pc * 4] = s;
    }
}

// ---------------- Kernel 3: merge chunk partials -> feats ----------------
__global__ __launch_bounds__(256) void k_attn_merge(
    const float* __restrict__ attnp,
    const float* __restrict__ rot, const float* __restrict__ trans,
    float* __restrict__ feats)
{
    const int i = blockIdx.x;
    const int tid = threadIdx.x;
    __shared__ float sm_m[32], sm_l[32], sW[32], sL[8], pts_s[96];

    const float* base = attnp + (size_t)i * 4 * PCH;
    if (tid < 32) {
        int jcx = tid >> 3, h = tid & 7;
        sm_m[jcx * 8 + h] = base[jcx * PCH + 1248 + h];
        sm_l[jcx * 8 + h] = base[jcx * PCH + 1256 + h];
    }
    __syncthreads();
    if (tid < 8) {
        const int h = tid;
        float M = fmaxf(fmaxf(sm_m[h], sm_m[8 + h]), fmaxf(sm_m[16 + h], sm_m[24 + h]));
        float L = 0.f;
        #pragma unroll
        for (int jcx = 0; jcx < 4; ++jcx) {
            float w = __expf(sm_m[jcx * 8 + h] - M);
            L += sm_l[jcx * 8 + h] * w;
            sW[jcx * 8 + h] = w;
        }
        sL[h] = L;
    }
    __syncthreads();

    {   // out_pair
        const int h = tid >> 5, pq = tid & 31;
        float4 s = make_float4(0, 0, 0, 0);
        #pragma unroll
        for (int jcx = 0; jcx < 4; ++jcx) {
            float4 a = *(const float4*)&base[jcx * PCH + h * 128 + pq * 4];
            float w = sW[jcx * 8 + h];
            s.x += a.x * w; s.y += a.y * w; s.z += a.z * w; s.w += a.w * w;
        }
        float inv = 1.f / sL[h];
        s.x *= inv; s.y *= inv; s.z *= inv; s.w *= inv;
        ((float4*)&feats[(size_t)i * 1280 + 256])[tid] = s;
    }
    if (tid < 32) {      // out_s
        const int h = tid >> 2;
        float4 s = make_float4(0, 0, 0, 0);
        #pragma unroll
        for (int jcx = 0; jcx < 4; ++jcx) {
            float4 a = *(const float4*)&base[jcx * PCH + 1024 + tid * 4];
            float w = sW[jcx * 8 + h];
            s.x += a.x * w; s.y += a.y * w; s.z += a.z * w; s.w += a.w * w;
        }
        float inv = 1.f / sL[h];
        s.x *= inv; s.y *= inv; s.z *= inv; s.w *= inv;
        ((float4*)&feats[(size_t)i * 1280])[tid] = s;
    } else if (tid < 56) {   // points
        const int pc = tid - 32;
        const int h = pc / 3;
        float4 s = make_float4(0, 0, 0, 0);
        #pragma unroll
        for (int jcx = 0; jcx < 4; ++jcx) {
            float4 a = *(const float4*)&base[jcx * PCH + 1152 + pc * 4];
            float w = sW[jcx * 8 + h];
            s.x += a.x * w; s.y += a.y * w; s.z += a.z * w; s.w += a.w * w;
        }
        float inv = 1.f / sL[h];
        s.x *= inv; s.y *= inv; s.z *= inv; s.w *= inv;
        ((float4*)pts_s)[pc] = s;
    }
    __syncthreads();

    if (tid < 32) {
        const float* R = &rot[(size_t)i * 9];
        const float* T = &trans[(size_t)i * 3];
        float px = pts_s[tid * 3 + 0] - T[0];
        float py = pts_s[tid * 3 + 1] - T[1];
        float pz = pts_s[tid * 3 + 2] - T[2];
        float n2 = 0.f;
        float* fo = feats + (size_t)i * 1280;
        #pragma unroll
        for (int r = 0; r < 3; ++r) {
            float lr = px * R[r * 3 + 0] + py * R[r * 3 + 1] + pz * R[r * 3 + 2];
            fo[128 + tid * 3 + r] = lr;
            n2 += lr * lr;
        }
        fo[224 + tid] = sqrtf(n2 + 1e-8f);
    }
}

// ---------------- Kernel 5a: final GEMM, split-K, 128x128 tile ----------------
__global__ __launch_bounds__(256) void k_final_gemm(
    const float* __restrict__ feats, const float* __restrict__ Wout,
    float* __restrict__ partial)
{
    const int m0 = blockIdx.x * 128;
    const int n0 = blockIdx.y * 128;
    const int ks = blockIdx.z;
    const int tid = threadIdx.x;
    const int k0 = ks * KPER;
    __shared__ float As[16][132];
    __shared__ float Bs[16][132];
    const int tx = tid & 15, ty = tid >> 4;
    float acc[8][8] = {};

    for (int kt = 0; kt < KPER; kt += 16) {
        #pragma unroll
        for (int it = 0; it < 2; ++it) {
            const int l = tid + it * 256;
            const int row = l >> 2, kq = l & 3;
            float4 a = *(const float4*)&feats[(size_t)(m0 + row) * 1280 + k0 + kt + kq * 4];
            As[kq * 4 + 0][row] = a.x; As[kq * 4 + 1][row] = a.y;
            As[kq * 4 + 2][row] = a.z; As[kq * 4 + 3][row] = a.w;
            const int kk = l >> 5, nq = l & 31;
            float4 b = *(const float4*)&Wout[(size_t)(k0 + kt + kk) * 384 + n0 + nq * 4];
            *(float4*)&Bs[kk][nq * 4] = b;
        }
        __syncthreads();
        #pragma unroll
        for (int k = 0; k < 16; ++k) {
            float4 a0 = *(const float4*)&As[k][ty * 8];
            float4 a1 = *(const float4*)&As[k][ty * 8 + 4];
            float4 b0 = *(const float4*)&Bs[k][tx * 8];
            float4 b1 = *(const float4*)&Bs[k][tx * 8 + 4];
            float am[8] = {a0.x, a0.y, a0.z, a0.w, a1.x, a1.y, a1.z, a1.w};
            float bn[8] = {b0.x, b0.y, b0.z, b0.w, b1.x, b1.y, b1.z, b1.w};
            #pragma unroll
            for (int r = 0; r < 8; ++r)
                #pragma unroll
                for (int c = 0; c < 8; ++c)
                    acc[r][c] += am[r] * bn[c];
        }
        __syncthreads();
    }
    float* po = partial + (size_t)ks * (512 * 384);
    #pragma unroll
    for (int r = 0; r < 8; ++r) {
        *(float4*)&po[(size_t)(m0 + ty * 8 + r) * 384 + n0 + tx * 8]     = *(float4*)&acc[r][0];
        *(float4*)&po[(size_t)(m0 + ty * 8 + r) * 384 + n0 + tx * 8 + 4] = *(float4*)&acc[r][4];
    }
}

// ---------------- Kernel 5b: split-K reduce + bias ----------------
__global__ __launch_bounds__(256) void k_reduce(
    const float* __restrict__ partial, const float* __restrict__ bout,
    float* __restrict__ out)
{
    const int f = blockIdx.x * 256 + threadIdx.x;
    const int e = f * 4;
    const int col = e % 384;
    float4 acc = *(const float4*)&bout[col];
    #pragma unroll
    for (int s = 0; s < KSL; ++s) {
        float4 p = *(const float4*)&partial[(size_t)s * (512 * 384) + e];
        acc.x += p.x; acc.y += p.y; acc.z += p.z; acc.w += p.w;
    }
    *(float4*)&out[e] = acc;
}

extern "C" void kernel_launch(void* const* d_in, const int* in_sizes, int n_in,
                              void* d_out, int out_size, void* d_ws, size_t ws_size,
                              hipStream_t stream) {
    const float* x     = (const float*)d_in[0];
    const float* pair  = (const float*)d_in[1];
    const float* rot   = (const float*)d_in[2];
    const float* trans = (const float*)d_in[3];
    const float* Wsq   = (const float*)d_in[4];
    const float* Wsk   = (const float*)d_in[5];
    const float* Wsv   = (const float*)d_in[6];
    const float* Wpq   = (const float*)d_in[7];
    const float* Wpk   = (const float*)d_in[8];
    const float* Wpv   = (const float*)d_in[9];
    const float* Wpair = (const float*)d_in[10];
    const float* bpair = (const float*)d_in[11];
    const float* pwts  = (const float*)d_in[12];
    const float* Wout  = (const float*)d_in[13];
    const float* bout  = (const float*)d_in[14];

    float* ws    = (float*)d_ws;
    float* qs    = ws;                       // 512*128
    float* ks    = qs + 512 * 128;
    float* vs    = ks + 512 * 128;
    float* qp    = vs + 512 * 128;           // 512*96
    float* kp    = qp + 512 * 96;
    float* vp    = kp + 512 * 96;
    float* feats = vp + 512 * 96;            // 512*1280
    float* scratch = feats + 512 * 1280;
    float* attnp = scratch + 1048576;        // 2048*1264
    float* plq   = attnp + 2048 * PCH;
    float* plk   = plq + 512 * 96;
    float* plv   = plk + 512 * 96;
    float* partial = scratch;                // KSL*512*384 (attnp dead after merge)

    k_proj_gemm<<<dim3(8, 21), 256, 0, stream>>>(x, Wsq, Wsk, Wsv, Wpq, Wpk, Wpv,
                                                 qs, ks, vs, plq, plk, plv);
    k_frames<<<192, 256, 0, stream>>>(plq, plk, plv, rot, trans, qp, kp, vp);
    k_attn<<<dim3(4, 512), 256, 0, stream>>>(pair, qs, ks, qp, kp, vs, vp,
                                             Wpair, bpair, pwts, attnp);
    k_attn_merge<<<512, 256, 0, stream>>>(attnp, rot, trans, feats);
    k_final_gemm<<<dim3(4, 3, KSL), 256, 0, stream>>>(feats, Wout, partial);
    k_reduce<<<192, 256, 0, stream>>>(partial, bout, (float*)d_out);
}